// Round 1
// baseline (174.691 us; speedup 1.0000x reference)
//
#include <hip/hip_runtime.h>

// upfirdn2d(x, k, up=2, down=1, pad=(2,1)) with separable k1 = [.25,.75,.75,.25]
// Closed form per axis:
//   out[2i]   = 0.25*x[i-1] + 0.75*x[i]
//   out[2i+1] = 0.75*x[i]   + 0.25*x[i+1]     (zero outside [0,H))
// Fixed problem size: data [8,64,256,256] f32 -> out [8,64,512,512] f32.

#define HH   256
#define WW   256
#define NIMG 512          // 8*64 images, depthwise
#define TPW  64           // threads per input row = WW/4

__global__ __launch_bounds__(256) void upscale2x_kernel(
        const float* __restrict__ in, float* __restrict__ out) {
    const int flat = blockIdx.x * 256 + threadIdx.x;
    const int t   = flat & (TPW - 1);        // 4-input-col group
    const int i   = (flat >> 6) & (HH - 1);  // input row
    const int img = flat >> 14;              // image index

    const float* ip = in + (size_t)img * (HH * WW);
    const int jb = 4 * t;

    // cols jb-1 .. jb+4 of rows i-1, i, i+1 (zeros outside)
    float xm[6], x0[6], xp[6];

    {   // row i — always valid
        const float4 v = *reinterpret_cast<const float4*>(ip + (size_t)i * WW + jb);
        x0[1] = v.x; x0[2] = v.y; x0[3] = v.z; x0[4] = v.w;
        x0[0] = (t > 0)       ? ip[(size_t)i * WW + jb - 1] : 0.f;
        x0[5] = (t < TPW - 1) ? ip[(size_t)i * WW + jb + 4] : 0.f;
    }
    if (i > 0) {
        const float4 v = *reinterpret_cast<const float4*>(ip + (size_t)(i - 1) * WW + jb);
        xm[1] = v.x; xm[2] = v.y; xm[3] = v.z; xm[4] = v.w;
        xm[0] = (t > 0)       ? ip[(size_t)(i - 1) * WW + jb - 1] : 0.f;
        xm[5] = (t < TPW - 1) ? ip[(size_t)(i - 1) * WW + jb + 4] : 0.f;
    } else {
        #pragma unroll
        for (int m = 0; m < 6; ++m) xm[m] = 0.f;
    }
    if (i < HH - 1) {
        const float4 v = *reinterpret_cast<const float4*>(ip + (size_t)(i + 1) * WW + jb);
        xp[1] = v.x; xp[2] = v.y; xp[3] = v.z; xp[4] = v.w;
        xp[0] = (t > 0)       ? ip[(size_t)(i + 1) * WW + jb - 1] : 0.f;
        xp[5] = (t < TPW - 1) ? ip[(size_t)(i + 1) * WW + jb + 4] : 0.f;
    } else {
        #pragma unroll
        for (int m = 0; m < 6; ++m) xp[m] = 0.f;
    }

    // Horizontal pass: 8 output-col values per row.
    // local input col m -> x arrays: x[j-1]=a[m], x[j]=a[m+1], x[j+1]=a[m+2]
    float hm[8], h0[8], hp[8];
    #pragma unroll
    for (int m = 0; m < 4; ++m) {
        hm[2*m]     = 0.25f * xm[m]     + 0.75f * xm[m + 1];
        hm[2*m + 1] = 0.75f * xm[m + 1] + 0.25f * xm[m + 2];
        h0[2*m]     = 0.25f * x0[m]     + 0.75f * x0[m + 1];
        h0[2*m + 1] = 0.75f * x0[m + 1] + 0.25f * x0[m + 2];
        hp[2*m]     = 0.25f * xp[m]     + 0.75f * xp[m + 1];
        hp[2*m + 1] = 0.75f * xp[m + 1] + 0.25f * xp[m + 2];
    }

    // Vertical pass: out rows 2i (blend i-1,i) and 2i+1 (blend i,i+1).
    float ve[8], vo[8];
    #pragma unroll
    for (int c = 0; c < 8; ++c) {
        ve[c] = 0.25f * hm[c] + 0.75f * h0[c];
        vo[c] = 0.75f * h0[c] + 0.25f * hp[c];
    }

    float* op = out + (size_t)img * (size_t)(2 * HH * 2 * WW)
                    + (size_t)(2 * i) * (2 * WW) + 8 * t;
    *reinterpret_cast<float4*>(op)              = make_float4(ve[0], ve[1], ve[2], ve[3]);
    *reinterpret_cast<float4*>(op + 4)          = make_float4(ve[4], ve[5], ve[6], ve[7]);
    *reinterpret_cast<float4*>(op + 2 * WW)     = make_float4(vo[0], vo[1], vo[2], vo[3]);
    *reinterpret_cast<float4*>(op + 2 * WW + 4) = make_float4(vo[4], vo[5], vo[6], vo[7]);
}

extern "C" void kernel_launch(void* const* d_in, const int* in_sizes, int n_in,
                              void* d_out, int out_size, void* d_ws, size_t ws_size,
                              hipStream_t stream) {
    const float* in = (const float*)d_in[0];   // d_in[1] (the 4x4 kernel) is a
    float* outp = (float*)d_out;               // fixed constant; weights hard-coded.
    const int total  = NIMG * HH * TPW;        // 8,388,608 threads
    const int blocks = total / 256;            // 32,768 blocks
    upscale2x_kernel<<<blocks, 256, 0, stream>>>(in, outp);
}

// Round 2
// 152.838 us; speedup vs baseline: 1.1430x; 1.1430x over previous
//
#include <hip/hip_runtime.h>

// upfirdn2d(x, k, up=2, down=1, pad=(2,1)), separable k1 = [.25,.75,.75,.25]:
//   out[2j]   = 0.25*x[j-1] + 0.75*x[j]
//   out[2j+1] = 0.75*x[j]   + 0.25*x[j+1]    (zero outside [0,N))
// Fixed size: [8,64,256,256] f32 -> [8,64,512,512] f32.
//
// Layout: one WAVE covers a full input row (64 lanes x 4 cols = 256).
// Column halos come from __shfl_up/__shfl_down (no scalar global loads).
// Each thread owns a strip of 4 input rows -> 8 output rows, streaming the
// horizontal pass (h_prev/h_cur/h_next) so each input row is loaded once per
// strip; vertical read amplification drops from 3x to 1.5x.

#define HH   256
#define WW   256
#define NIMG 512    // 8*64 depthwise images
#define RG   64     // row-groups per image (4 input rows each)

__device__ __forceinline__ void hpass(const float* __restrict__ ip, int ri,
                                      int lane, float h[8]) {
    float x0, x1, x2, x3, xl, xr;
    if (ri >= 0 && ri < HH) {   // wave-uniform branch
        const float4 v = *reinterpret_cast<const float4*>(ip + (size_t)ri * WW + 4 * lane);
        x0 = v.x; x1 = v.y; x2 = v.z; x3 = v.w;
        xl = __shfl_up(v.w, 1);   if (lane == 0)  xl = 0.f;
        xr = __shfl_down(v.x, 1); if (lane == 63) xr = 0.f;
    } else {
        x0 = x1 = x2 = x3 = xl = xr = 0.f;
    }
    h[0] = 0.25f * xl + 0.75f * x0;
    h[1] = 0.75f * x0 + 0.25f * x1;
    h[2] = 0.25f * x0 + 0.75f * x1;
    h[3] = 0.75f * x1 + 0.25f * x2;
    h[4] = 0.25f * x1 + 0.75f * x2;
    h[5] = 0.75f * x2 + 0.25f * x3;
    h[6] = 0.25f * x2 + 0.75f * x3;
    h[7] = 0.75f * x3 + 0.25f * xr;
}

__device__ __forceinline__ void store8(float* __restrict__ p, float wa,
                                       const float a[8], float wb, const float b[8]) {
    const float4 u = make_float4(wa * a[0] + wb * b[0], wa * a[1] + wb * b[1],
                                 wa * a[2] + wb * b[2], wa * a[3] + wb * b[3]);
    const float4 v = make_float4(wa * a[4] + wb * b[4], wa * a[5] + wb * b[5],
                                 wa * a[6] + wb * b[6], wa * a[7] + wb * b[7]);
    *reinterpret_cast<float4*>(p)     = u;
    *reinterpret_cast<float4*>(p + 4) = v;
}

__global__ __launch_bounds__(256) void upscale2x_kernel(
        const float* __restrict__ in, float* __restrict__ out) {
    const int lane = threadIdx.x & 63;
    const int wid  = blockIdx.x * 4 + (threadIdx.x >> 6);  // global wave id
    const int rg   = wid & (RG - 1);                       // row-group in image
    const int img  = wid >> 6;
    const int i0   = rg * 4;                               // first input row of strip

    const float* ip = in + (size_t)img * (HH * WW);
    float* op = out + (size_t)img * (size_t)(4 * HH * WW)
                    + (size_t)(2 * i0) * (2 * WW) + 8 * lane;

    float hprev[8], hcur[8], hnext[8];
    hpass(ip, i0 - 1, lane, hprev);
    hpass(ip, i0,     lane, hcur);

    // output row 2*i0 (even): 0.25*h[i-1] + 0.75*h[i]
    store8(op, 0.25f, hprev, 0.75f, hcur);

    #pragma unroll
    for (int k = 0; k < 4; ++k) {
        hpass(ip, i0 + k + 1, lane, hnext);
        // odd row 2*(i0+k)+1: 0.75*h[i] + 0.25*h[i+1]
        store8(op + (size_t)(2 * k + 1) * (2 * WW), 0.75f, hcur, 0.25f, hnext);
        if (k < 3) {
            // even row 2*(i0+k+1): 0.25*h[i] + 0.75*h[i+1]
            store8(op + (size_t)(2 * k + 2) * (2 * WW), 0.25f, hcur, 0.75f, hnext);
        }
        #pragma unroll
        for (int m = 0; m < 8; ++m) hcur[m] = hnext[m];
    }
}

extern "C" void kernel_launch(void* const* d_in, const int* in_sizes, int n_in,
                              void* d_out, int out_size, void* d_ws, size_t ws_size,
                              hipStream_t stream) {
    const float* in = (const float*)d_in[0];   // d_in[1] (4x4 kernel) is constant; hard-coded
    float* outp = (float*)d_out;
    const int total  = NIMG * RG * 64;         // 2,097,152 threads (one wave per row-strip)
    const int blocks = total / 256;            // 8192 blocks
    upscale2x_kernel<<<blocks, 256, 0, stream>>>(in, outp);
}

// Round 4
// 103.083 us; speedup vs baseline: 1.6947x; 1.4827x over previous
//
#include <hip/hip_runtime.h>

// upfirdn2d(x, k, up=2, down=1, pad=(2,1)), separable k1 = [.25,.75,.75,.25]:
//   out[2j]   = 0.25*x[j-1] + 0.75*x[j]
//   out[2j+1] = 0.75*x[j]   + 0.25*x[j+1]   (zero outside [0,N))
// Fixed size: [8,64,256,256] f32 -> [8,64,512,512] f32.
//
// One wave covers a full input row. Lane l owns input cols {2l,2l+1} (L) and
// {128+2l,128+2l+1} (R) -> output cols {4l..4l+3} and {256+4l..+3}, so every
// output-row store is two fully CONTIGUOUS 1 KiB dwordx4 instructions (R1's
// 32B-strided stores doubled store requests). Halos via 6 shuffles/row.
// 16-row strips cut read amplification to 18/16 = 1.125x. NT stores keep L2
// for the (reused) input halo rows; output is never re-read.

#define HH    256
#define WW    256
#define NIMG  512   // 8*64 depthwise images
#define SROWS 16    // input rows per wave-strip
#define SPI   (HH / SROWS)   // 16 strips per image

typedef float v4f __attribute__((ext_vector_type(4)));  // NT-store-compatible

__device__ __forceinline__ void loadrow(const float* __restrict__ ip, int ri,
                                        int lane, float2& L, float2& R) {
    if (ri >= 0 && ri < HH) {   // wave-uniform
        const float* r = ip + (size_t)ri * WW;
        L = *reinterpret_cast<const float2*>(r + 2 * lane);
        R = *reinterpret_cast<const float2*>(r + 128 + 2 * lane);
    } else {
        L = make_float2(0.f, 0.f);
        R = make_float2(0.f, 0.f);
    }
}

// h[0..3] = out cols 4l..4l+3 ; h[4..7] = out cols 256+4l..+3 (horizontal pass)
__device__ __forceinline__ void hpass(float2 L, float2 R, int lane, float h[8]) {
    float Lxl = __shfl_up(L.y, 1);             if (lane == 0)  Lxl = 0.f;       // x[2l-1]
    float Lxr = __shfl(L.x, (lane + 1) & 63);                                   // x[2l+2]
    float Rx0 = __shfl(R.x, 0);                if (lane == 63) Lxr = Rx0;       //   seam: x[128]
    float Rxl = __shfl(R.y, (lane + 63) & 63);                                  // x[128+2l-1]
    float Ly63 = __shfl(L.y, 63);              if (lane == 0)  Rxl = Ly63;      //   seam: x[127]
    float Rxr = __shfl_down(R.x, 1);           if (lane == 63) Rxr = 0.f;       // x[128+2l+2]
    h[0] = 0.25f * Lxl + 0.75f * L.x;
    h[1] = 0.75f * L.x + 0.25f * L.y;
    h[2] = 0.25f * L.x + 0.75f * L.y;
    h[3] = 0.75f * L.y + 0.25f * Lxr;
    h[4] = 0.25f * Rxl + 0.75f * R.x;
    h[5] = 0.75f * R.x + 0.25f * R.y;
    h[6] = 0.25f * R.x + 0.75f * R.y;
    h[7] = 0.75f * R.y + 0.25f * Rxr;
}

__device__ __forceinline__ void storerow(float* __restrict__ row, int lane,
                                         float wa, const float a[8],
                                         float wb, const float b[8]) {
    v4f u = { wa*a[0]+wb*b[0], wa*a[1]+wb*b[1], wa*a[2]+wb*b[2], wa*a[3]+wb*b[3] };
    v4f v = { wa*a[4]+wb*b[4], wa*a[5]+wb*b[5], wa*a[6]+wb*b[6], wa*a[7]+wb*b[7] };
    __builtin_nontemporal_store(u, reinterpret_cast<v4f*>(row + 4 * lane));
    __builtin_nontemporal_store(v, reinterpret_cast<v4f*>(row + 256 + 4 * lane));
}

__global__ __launch_bounds__(256) void upscale2x_kernel(
        const float* __restrict__ in, float* __restrict__ out) {
    const int lane = threadIdx.x & 63;
    const int wid  = blockIdx.x * 4 + (threadIdx.x >> 6);
    const int s    = wid & (SPI - 1);
    const int img  = wid >> 4;                 // wid / SPI
    const int i0   = s * SROWS;

    const float* ip = in + (size_t)img * (HH * WW);
    float* ob = out + (size_t)img * (size_t)(4 * HH * WW)
                    + (size_t)(2 * i0) * (2 * WW);

    float2 Lc, Rc;
    float ha[8], hb[8];
    loadrow(ip, i0 - 1, lane, Lc, Rc);
    hpass(Lc, Rc, lane, ha);                   // h[i0-1]
    loadrow(ip, i0, lane, Lc, Rc);
    hpass(Lc, Rc, lane, hb);                   // h[i0]
    storerow(ob, lane, 0.25f, ha, 0.75f, hb);  // even row 2*i0

    #pragma unroll 3
    for (int k = 0; k < SROWS - 1; ++k) {      // hb = h[i0+k]
        loadrow(ip, i0 + k + 1, lane, Lc, Rc);
        hpass(Lc, Rc, lane, ha);               // ha = h[i0+k+1]
        storerow(ob + (size_t)(2*k+1) * (2*WW), lane, 0.75f, hb, 0.25f, ha); // odd 2i+1
        storerow(ob + (size_t)(2*k+2) * (2*WW), lane, 0.25f, hb, 0.75f, ha); // even 2i+2
        #pragma unroll
        for (int m = 0; m < 8; ++m) hb[m] = ha[m];
    }
    // tail: k = SROWS-1 -> only the odd row (next even row belongs to next strip)
    loadrow(ip, i0 + SROWS, lane, Lc, Rc);
    hpass(Lc, Rc, lane, ha);                   // h[i0+16] (zeros past image end)
    storerow(ob + (size_t)(2*SROWS - 1) * (2*WW), lane, 0.75f, hb, 0.25f, ha);
}

extern "C" void kernel_launch(void* const* d_in, const int* in_sizes, int n_in,
                              void* d_out, int out_size, void* d_ws, size_t ws_size,
                              hipStream_t stream) {
    const float* in = (const float*)d_in[0];   // d_in[1] (4x4 kernel) constant; hard-coded
    float* outp = (float*)d_out;
    const int waves  = NIMG * SPI;             // 8192 waves, one per 16-row strip
    const int blocks = waves / 4;              // 2048 blocks of 256 threads
    upscale2x_kernel<<<blocks, 256, 0, stream>>>(in, outp);
}